// Round 13
// baseline (543.647 us; speedup 1.0000x reference)
//
#include <hip/hip_runtime.h>
#include <cstdint>
#include <cstddef>

#define NN 100000
#define NE 1600000
#define FD 128
#define NXCD 8
#define RNODES ((NN + NXCD - 1) / NXCD)   // 12500 nodes per XCD range
#define CAP 208192                        // per-bucket capacity (E/8 + 8k slack)

typedef int vi4 __attribute__((ext_vector_type(4)));
typedef __attribute__((ext_vector_type(8))) short bf16x8;
typedef __attribute__((ext_vector_type(4))) float f32x4;

// ---- bf16 helpers (RNE), storage-only precision reduction ----
__device__ __forceinline__ float bf_lo(uint32_t u) { return __uint_as_float(u << 16); }
__device__ __forceinline__ float bf_hi(uint32_t u) { return __uint_as_float(u & 0xffff0000u); }
__device__ __forceinline__ uint32_t bf_pack(float a, float b) {
    uint32_t ua = __float_as_uint(a), ub = __float_as_uint(b);
    ua += 0x7fffu + ((ua >> 16) & 1u);
    ub += 0x7fffu + ((ub >> 16) & 1u);
    return (ua >> 16) | (ub & 0xffff0000u);
}
__device__ __forceinline__ unsigned short bf1(float a) {
    uint32_t u = __float_as_uint(a);
    u += 0x7fffu + ((u >> 16) & 1u);
    return (unsigned short)(u >> 16);
}

// ---------------- W pre-convert: fp32 -> bf16 (once, numerics identical) ----
__global__ __launch_bounds__(256) void k_wcvt(const float* __restrict__ W1,
                                              const float* __restrict__ W2,
                                              unsigned short* __restrict__ Wb1,
                                              unsigned short* __restrict__ Wb2) {
    int idx4 = (blockIdx.x * 256 + threadIdx.x) * 4;
    if (idx4 < FD * FD) {
        float4 a = *(const float4*)(W1 + idx4);
        ushort4 o;
        o.x = bf1(a.x); o.y = bf1(a.y); o.z = bf1(a.z); o.w = bf1(a.w);
        *(ushort4*)(Wb1 + idx4) = o;
        float4 b = *(const float4*)(W2 + idx4);
        ushort4 p;
        p.x = bf1(b.x); p.y = bf1(b.y); p.z = bf1(b.z); p.w = bf1(b.w);
        *(ushort4*)(Wb2 + idx4) = p;
    }
}

// ---------------- stage 1: bucket partition (each edge read ONCE) ----------
__global__ __launch_bounds__(256) void k_part(const int* __restrict__ src,
                                              const int* __restrict__ dst,
                                              uint32_t* __restrict__ bkt,
                                              int* __restrict__ bcnt, int e) {
    __shared__ int scnt[8];
    __shared__ int sbase[8];
    if (threadIdx.x < 8) scnt[threadIdx.x] = 0;
    __syncthreads();
    const int base = blockIdx.x * 1024 + threadIdx.x * 4;
    const bool valid = base < e;           // e % 4 == 0
    int b_[4]; int r_[4]; uint32_t u_[4];
    if (valid) {
        vi4 d4 = __builtin_nontemporal_load((const vi4*)(dst + base));
        vi4 s4 = __builtin_nontemporal_load((const vi4*)(src + base));
        #pragma unroll
        for (int j = 0; j < 4; ++j) {
            int d = d4[j], s = s4[j];
            int b = d / RNODES;
            b_[j] = b;
            u_[j] = ((uint32_t)(d - b * RNODES) << 17) | (uint32_t)s;
            r_[j] = atomicAdd(&scnt[b], 1);   // LDS rank within block-bucket
        }
    }
    __syncthreads();
    if (threadIdx.x < 8)
        sbase[threadIdx.x] = atomicAdd(&bcnt[threadIdx.x], scnt[threadIdx.x]);
    __syncthreads();
    if (valid) {
        #pragma unroll
        for (int j = 0; j < 4; ++j) {
            int b = b_[j];
            bkt[(size_t)b * CAP + sbase[b] + r_[j]] = u_[j];
        }
    }
}

// ---------------- stage 2: per-XCD degree histogram from bucket ------------
__global__ __launch_bounds__(256) void k_hist2(const uint32_t* __restrict__ bkt,
                                               const int* __restrict__ bcnt,
                                               int* __restrict__ cnt) {
    const int xcd  = blockIdx.x & 7;
    const int blk  = blockIdx.x >> 3;
    const int nblk = (int)(gridDim.x >> 3);
    const int m = bcnt[xcd];
    const uint32_t* B = bkt + (size_t)xcd * CAP;
    const int lo = xcd * RNODES;
    for (int i = blk * 256 + threadIdx.x; i < m; i += nblk * 256)
        atomicAdd(&cnt[lo + (int)(B[i] >> 17)], 1);
}

// ---------------- exclusive scan (3 kernels) ----------------
__global__ __launch_bounds__(1024) void k_scan1(const int* __restrict__ cnt,
                                                int* __restrict__ excl,
                                                int* __restrict__ bsum, int n) {
    __shared__ int sh[1024];
    int i = blockIdx.x * 1024 + threadIdx.x;
    int v = (i < n) ? cnt[i] : 0;
    sh[threadIdx.x] = v;
    __syncthreads();
    for (int off = 1; off < 1024; off <<= 1) {
        int t = (threadIdx.x >= off) ? sh[threadIdx.x - off] : 0;
        __syncthreads();
        sh[threadIdx.x] += t;
        __syncthreads();
    }
    if (i < n) excl[i] = sh[threadIdx.x] - v;   // exclusive
    if (threadIdx.x == 1023) bsum[blockIdx.x] = sh[1023];
}

__global__ void k_scan2(int* __restrict__ bsum, int nb) {
    __shared__ int sh[128];
    int t = threadIdx.x;
    int v = (t < nb) ? bsum[t] : 0;
    sh[t] = v;
    __syncthreads();
    for (int off = 1; off < 128; off <<= 1) {
        int u = (t >= off) ? sh[t - off] : 0;
        __syncthreads();
        sh[t] += u;
        __syncthreads();
    }
    if (t < nb) bsum[t] = sh[t] - v;   // exclusive block offsets
}

// finalize row_ptr, init cursor, compute dis = rsqrt(deg+1)
__global__ void k_scan3(int* __restrict__ excl, const int* __restrict__ bsum,
                        int* __restrict__ cursor, const int* __restrict__ cnt,
                        float* __restrict__ dis, int n, int e) {
    int i = blockIdx.x * blockDim.x + threadIdx.x;
    if (i < n) {
        int v = excl[i] + bsum[i >> 10];
        excl[i] = v;
        cursor[i] = v;
        dis[i] = rsqrtf((float)(cnt[i] + 1));
    }
    if (i == 0) excl[n] = e;
}

// ---------------- stage 4: per-XCD CSR fill from bucket --------------------
__global__ __launch_bounds__(256) void k_fill2(const uint32_t* __restrict__ bkt,
                                               const int* __restrict__ bcnt,
                                               int* __restrict__ cursor,
                                               uint2* __restrict__ colw,
                                               const float* __restrict__ dis) {
    const int xcd  = blockIdx.x & 7;
    const int blk  = blockIdx.x >> 3;
    const int nblk = (int)(gridDim.x >> 3);
    const int m = bcnt[xcd];
    const uint32_t* B = bkt + (size_t)xcd * CAP;
    const int lo = xcd * RNODES;
    for (int i = blk * 256 + threadIdx.x; i < m; i += nblk * 256) {
        uint32_t u = B[i];
        int s = (int)(u & 0x1FFFFu);
        int d = lo + (int)(u >> 17);
        int pos = atomicAdd(&cursor[d], 1);
        uint2 cw;
        cw.x = (uint32_t)s;
        cw.y = __float_as_uint(dis[s] * dis[d]);
        colw[pos] = cw;
    }
}

// ---------------- MFMA GEMM: H[n x 128] = X[n x 128] @ Wb[128 x 128] -> bf16 -
// 256 thr = 4 waves; wave computes 16 rows x 128 cols via 16x16x32 bf16 MFMA.
// Wb is pre-converted bf16; LDS stage is a pure transpose copy.
// C/D mapping (m89-verified): col=lane&15, row=(lane>>4)*4+j.
template <typename TIN>
__global__ __launch_bounds__(256) void k_gemm(const TIN* __restrict__ X,
                                              const unsigned short* __restrict__ Wb,
                                              unsigned short* __restrict__ H, int n) {
    __shared__ unsigned short Wl[128][136];   // [n][k] bf16
    const int t = threadIdx.x;
    #pragma unroll
    for (int c = 0; c < 8; ++c) {
        int idx8 = (c * 256 + t) * 8;        // 8 bf16 = 16B, within-row (8 | 128)
        int k  = idx8 >> 7;
        int nn = idx8 & 127;
        ushort4 v0 = *(const ushort4*)(Wb + idx8);
        ushort4 v1 = *(const ushort4*)(Wb + idx8 + 4);
        Wl[nn + 0][k] = v0.x; Wl[nn + 1][k] = v0.y;
        Wl[nn + 2][k] = v0.z; Wl[nn + 3][k] = v0.w;
        Wl[nn + 4][k] = v1.x; Wl[nn + 5][k] = v1.y;
        Wl[nn + 6][k] = v1.z; Wl[nn + 7][k] = v1.w;
    }
    __syncthreads();

    const int wave = t >> 6, lane = t & 63;
    const int row0 = blockIdx.x * 64 + wave * 16;
    if (row0 >= n) return;
    const int arow = row0 + (lane & 15);
    const int kb8  = (lane >> 4) * 8;

    bf16x8 a[4];
    if constexpr (sizeof(TIN) == 4) {
        const float* Xf = (const float*)X;
        #pragma unroll
        for (int kt = 0; kt < 4; ++kt) {
            const float* p = Xf + (size_t)arow * FD + kt * 32 + kb8;
            float4 u0 = *(const float4*)p;
            float4 u1 = *(const float4*)(p + 4);
            bf16x8 f;
            f[0] = (short)bf1(u0.x); f[1] = (short)bf1(u0.y);
            f[2] = (short)bf1(u0.z); f[3] = (short)bf1(u0.w);
            f[4] = (short)bf1(u1.x); f[5] = (short)bf1(u1.y);
            f[6] = (short)bf1(u1.z); f[7] = (short)bf1(u1.w);
            a[kt] = f;
        }
    } else {
        const unsigned short* Xb = (const unsigned short*)X;
        #pragma unroll
        for (int kt = 0; kt < 4; ++kt)
            a[kt] = *(const bf16x8*)(Xb + (size_t)arow * FD + kt * 32 + kb8);
    }

    const int ccol  = lane & 15;
    const int crow0 = row0 + (lane >> 4) * 4;
    #pragma unroll
    for (int nt = 0; nt < 8; ++nt) {
        f32x4 acc = {0.f, 0.f, 0.f, 0.f};
        const int bcol = nt * 16 + (lane & 15);
        #pragma unroll
        for (int kt = 0; kt < 4; ++kt) {
            bf16x8 b = *(const bf16x8*)&Wl[bcol][kt * 32 + kb8];
            acc = __builtin_amdgcn_mfma_f32_16x16x32_bf16(a[kt], b, acc, 0, 0, 0);
        }
        #pragma unroll
        for (int j = 0; j < 4; ++j)
            H[(size_t)(crow0 + j) * FD + nt * 16 + ccol] = bf1(acc[j]);
    }
}

// ---------------- 128-wide aggregation over bf16 rows --------------------
// FOUR nodes per wave; per node ceil(deg/16) masked 16-deep gather groups ->
// up to 64 independent 256B row loads in flight per wave. fp32 accumulation.
// MODE 0: writes relu rows (bf16). MODE 1: fused dot with W3 -> outf[i].
template <int MODE>
__global__ __launch_bounds__(256) void k_agg(const unsigned short* __restrict__ h,
                                             const float* __restrict__ dis,
                                             const int* __restrict__ rp,
                                             const uint2* __restrict__ colw,
                                             const float* __restrict__ bias,
                                             const float* __restrict__ W3,
                                             unsigned short* __restrict__ out,
                                             float* __restrict__ outf, int n) {
    const uint32_t* h32 = (const uint32_t*)h;   // 64 words per row
    int wid  = (int)((blockIdx.x * (size_t)blockDim.x + threadIdx.x) >> 6);
    int lane = threadIdx.x & 63;
    int w4 = __builtin_amdgcn_readfirstlane(wid);
    int i0 = 4 * w4;
    if (i0 >= n) return;

    int eb[5];
    #pragma unroll
    for (int k = 0; k < 5; ++k) {
        int idx = i0 + k;
        eb[k] = rp[idx < n ? idx : n];       // rows beyond n are empty
    }

    float2 acc[4];
    #pragma unroll
    for (int k = 0; k < 4; ++k) {
        int i = i0 + k;
        if (i < n) {
            float di = dis[i];
            float q  = di * di;
            uint32_t su = h32[(size_t)i * 64 + lane];
            acc[k].x = bf_lo(su) * q;
            acc[k].y = bf_hi(su) * q;
        } else { acc[k].x = 0.f; acc[k].y = 0.f; }
    }

    int ng[4], ngmax = 0;
    #pragma unroll
    for (int k = 0; k < 4; ++k) {
        ng[k] = (eb[k + 1] - eb[k] + 15) >> 4;
        ngmax = ng[k] > ngmax ? ng[k] : ngmax;
    }

    for (int g = 0; g < ngmax; ++g) {
        int s[4][16]; float wt[4][16]; uint32_t v[4][16];
        #pragma unroll
        for (int k = 0; k < 4; ++k) {
            if (g < ng[k]) {
                const int jb = eb[k] + g * 16;
                const int ee = eb[k + 1];
                if (jb + 16 <= ee) {
                    #pragma unroll
                    for (int q = 0; q < 16; ++q) {
                        uint2 cw = colw[jb + q];
                        s[k][q] = (int)cw.x; wt[k][q] = __uint_as_float(cw.y);
                    }
                } else {
                    #pragma unroll
                    for (int q = 0; q < 16; ++q) {
                        int idx = jb + q;
                        int c   = idx < ee ? idx : ee - 1;
                        uint2 cw = colw[c];
                        s[k][q]  = (int)cw.x;
                        wt[k][q] = idx < ee ? __uint_as_float(cw.y) : 0.f;
                    }
                }
            }
        }
        #pragma unroll
        for (int k = 0; k < 4; ++k) {
            if (g < ng[k]) {
                #pragma unroll
                for (int q = 0; q < 16; ++q)
                    v[k][q] = h32[(size_t)s[k][q] * 64 + lane];
            }
        }
        #pragma unroll
        for (int k = 0; k < 4; ++k) {
            if (g < ng[k]) {
                #pragma unroll
                for (int q = 0; q < 16; ++q) {
                    acc[k].x = fmaf(wt[k][q], bf_lo(v[k][q]), acc[k].x);
                    acc[k].y = fmaf(wt[k][q], bf_hi(v[k][q]), acc[k].y);
                }
            }
        }
    }

    float2 b = ((const float2*)bias)[lane];
    #pragma unroll
    for (int k = 0; k < 4; ++k) {
        acc[k].x = fmaxf(acc[k].x + b.x, 0.f);
        acc[k].y = fmaxf(acc[k].y + b.y, 0.f);
    }

    if (MODE == 0) {
        #pragma unroll
        for (int k = 0; k < 4; ++k) {
            if (i0 + k < n)
                ((uint32_t*)out)[(size_t)(i0 + k) * 64 + lane] =
                    bf_pack(acc[k].x, acc[k].y);
        }
    } else {
        float2 w3 = ((const float2*)W3)[lane];
        float d[4];
        #pragma unroll
        for (int k = 0; k < 4; ++k)
            d[k] = acc[k].x * w3.x + acc[k].y * w3.y;
        #pragma unroll
        for (int off = 32; off; off >>= 1) {
            #pragma unroll
            for (int k = 0; k < 4; ++k) d[k] += __shfl_xor(d[k], off);
        }
        if (lane == 0) {
            #pragma unroll
            for (int k = 0; k < 4; ++k)
                if (i0 + k < n) outf[i0 + k] = d[k];
        }
    }
}

// ---------------- scalar aggregation + bias + sigmoid (wave per node) ----------
__global__ __launch_bounds__(256) void k_agg1(const float* __restrict__ h3,
                                              const float* __restrict__ dis,
                                              const int* __restrict__ rp,
                                              const uint2* __restrict__ colw,
                                              const float* __restrict__ b3,
                                              float* __restrict__ out, int n) {
    int i    = (int)((blockIdx.x * (size_t)blockDim.x + threadIdx.x) >> 6);
    int lane = threadIdx.x & 63;
    if (i >= n) return;
    float di  = dis[i];
    float acc = (lane == 0) ? di * di * h3[i] : 0.f;
    const int e0 = rp[i], e1 = rp[i + 1];
    for (int base = e0 + lane; base < e1; base += 64) {
        uint2 cw = colw[base];
        acc = fmaf(__uint_as_float(cw.y), h3[(int)cw.x], acc);
    }
    #pragma unroll
    for (int off = 32; off; off >>= 1) acc += __shfl_xor(acc, off);
    if (lane == 0) {
        float v = acc + b3[0];
        out[i] = 1.f / (1.f + expf(-v));
    }
}

// ---------------- host launch ----------------
static inline size_t alg(size_t x) { return (x + 255) & ~(size_t)255; }

extern "C" void kernel_launch(void* const* d_in, const int* in_sizes, int n_in,
                              void* d_out, int out_size, void* d_ws, size_t ws_size,
                              hipStream_t stream) {
    const float* x   = (const float*)d_in[0];
    const int*   ei  = (const int*)d_in[1];     // [2, E]
    const float* W1  = (const float*)d_in[2];
    const float* b1  = (const float*)d_in[3];
    const float* W2  = (const float*)d_in[4];
    const float* b2  = (const float*)d_in[5];
    const float* W3  = (const float*)d_in[6];
    const float* b3  = (const float*)d_in[7];
    float*       out = (float*)d_out;

    const int n = NN, e = NE;
    const int* src = ei;
    const int* dst = ei + e;

    char* w = (char*)d_ws;
    float* dis    = (float*)w;  w += alg((size_t)n * 4);
    int*   cnt    = (int*)w;    w += alg((size_t)n * 4);
    int*   bcnt   = (int*)w;    w += alg((size_t)8 * 4);
    int*   rp     = (int*)w;    w += alg((size_t)(n + 1) * 4);
    int*   cursor = (int*)w;    w += alg((size_t)n * 4);
    int*   bsum   = (int*)w;    w += alg((size_t)128 * 4);
    uint32_t* bkt = (uint32_t*)w; w += alg((size_t)NXCD * CAP * 4);
    uint2* colw   = (uint2*)w;  w += alg((size_t)e * 8);
    unsigned short* bufA = (unsigned short*)w; w += alg((size_t)n * FD * 2);
    unsigned short* bufB = (unsigned short*)w; w += alg((size_t)n * FD * 2);
    unsigned short* Wb1  = (unsigned short*)w; w += alg((size_t)FD * FD * 2);
    unsigned short* Wb2  = (unsigned short*)w; w += alg((size_t)FD * FD * 2);
    float* h3     = (float*)w;  w += alg((size_t)n * 4);

    hipMemsetAsync(cnt, 0, (size_t)n * 4, stream);
    hipMemsetAsync(bcnt, 0, 8 * 4, stream);

    const int B = 256;
    const int gN = (n + B - 1) / B;
    const int nScan = (n + 1023) / 1024;   // 98
    const int nChunk = (e + 1023) / 1024;  // 1563

    k_wcvt<<<16, B, 0, stream>>>(W1, W2, Wb1, Wb2);
    k_part<<<nChunk, B, 0, stream>>>(src, dst, bkt, bcnt, e);
    k_hist2<<<2048, B, 0, stream>>>(bkt, bcnt, cnt);
    k_scan1<<<nScan, 1024, 0, stream>>>(cnt, rp, bsum, n);
    k_scan2<<<1, 128, 0, stream>>>(bsum, nScan);
    k_scan3<<<gN, B, 0, stream>>>(rp, bsum, cursor, cnt, dis, n, e);
    k_fill2<<<2048, B, 0, stream>>>(bkt, bcnt, cursor, colw, dis);

    const int gGemm = (n + 63) / 64;                    // 1563
    const int nWave4 = (n + 3) / 4;                     // four nodes per wave
    const int gWave4 = (nWave4 * 64 + B - 1) / B;       // blocks for k_agg
    const int gWave  = (n * 64 + B - 1) / B;            // wave per node (k_agg1)

    // layer 1
    k_gemm<float><<<gGemm, B, 0, stream>>>(x, Wb1, bufA, n);
    k_agg<0><<<gWave4, B, 0, stream>>>(bufA, dis, rp, colw, b1, W3, bufB, h3, n);
    // layer 2 (+ fused layer-3 matvec)
    k_gemm<unsigned short><<<gGemm, B, 0, stream>>>(bufB, Wb2, bufA, n);
    k_agg<1><<<gWave4, B, 0, stream>>>(bufA, dis, rp, colw, b2, W3, bufB, h3, n);
    // layer 3
    k_agg1<<<gWave, B, 0, stream>>>(h3, dis, rp, colw, b3, out, n);
}

// Round 14
// 488.659 us; speedup vs baseline: 1.1125x; 1.1125x over previous
//
#include <hip/hip_runtime.h>
#include <cstdint>
#include <cstddef>

#define NN 100000
#define NE 1600000
#define FD 128
#define NXCD 8
#define RNODES ((NN + NXCD - 1) / NXCD)   // 12500 nodes per XCD range
#define CAP 208192                        // per-bucket capacity (E/8 + 8k slack)

typedef int vi4 __attribute__((ext_vector_type(4)));
typedef __attribute__((ext_vector_type(8))) short bf16x8;
typedef __attribute__((ext_vector_type(4))) float f32x4;

// ---- bf16 helpers (RNE), storage-only precision reduction ----
__device__ __forceinline__ float bf_lo(uint32_t u) { return __uint_as_float(u << 16); }
__device__ __forceinline__ float bf_hi(uint32_t u) { return __uint_as_float(u & 0xffff0000u); }
__device__ __forceinline__ uint32_t bf_pack(float a, float b) {
    uint32_t ua = __float_as_uint(a), ub = __float_as_uint(b);
    ua += 0x7fffu + ((ua >> 16) & 1u);
    ub += 0x7fffu + ((ub >> 16) & 1u);
    return (ua >> 16) | (ub & 0xffff0000u);
}
__device__ __forceinline__ unsigned short bf1(float a) {
    uint32_t u = __float_as_uint(a);
    u += 0x7fffu + ((u >> 16) & 1u);
    return (unsigned short)(u >> 16);
}

// ---------------- W pre-convert: fp32 -> bf16 (once, numerics identical) ----
__global__ __launch_bounds__(256) void k_wcvt(const float* __restrict__ W1,
                                              const float* __restrict__ W2,
                                              unsigned short* __restrict__ Wb1,
                                              unsigned short* __restrict__ Wb2) {
    int idx4 = (blockIdx.x * 256 + threadIdx.x) * 4;
    if (idx4 < FD * FD) {
        float4 a = *(const float4*)(W1 + idx4);
        ushort4 o;
        o.x = bf1(a.x); o.y = bf1(a.y); o.z = bf1(a.z); o.w = bf1(a.w);
        *(ushort4*)(Wb1 + idx4) = o;
        float4 b = *(const float4*)(W2 + idx4);
        ushort4 p;
        p.x = bf1(b.x); p.y = bf1(b.y); p.z = bf1(b.z); p.w = bf1(b.w);
        *(ushort4*)(Wb2 + idx4) = p;
    }
}

// ---------------- stage 1: bucket partition (each edge read ONCE) ----------
__global__ __launch_bounds__(256) void k_part(const int* __restrict__ src,
                                              const int* __restrict__ dst,
                                              uint32_t* __restrict__ bkt,
                                              int* __restrict__ bcnt, int e) {
    __shared__ int scnt[8];
    __shared__ int sbase[8];
    if (threadIdx.x < 8) scnt[threadIdx.x] = 0;
    __syncthreads();
    const int base = blockIdx.x * 1024 + threadIdx.x * 4;
    const bool valid = base < e;           // e % 4 == 0
    int b_[4]; int r_[4]; uint32_t u_[4];
    if (valid) {
        vi4 d4 = __builtin_nontemporal_load((const vi4*)(dst + base));
        vi4 s4 = __builtin_nontemporal_load((const vi4*)(src + base));
        #pragma unroll
        for (int j = 0; j < 4; ++j) {
            int d = d4[j], s = s4[j];
            int b = d / RNODES;
            b_[j] = b;
            u_[j] = ((uint32_t)(d - b * RNODES) << 17) | (uint32_t)s;
            r_[j] = atomicAdd(&scnt[b], 1);   // LDS rank within block-bucket
        }
    }
    __syncthreads();
    if (threadIdx.x < 8)
        sbase[threadIdx.x] = atomicAdd(&bcnt[threadIdx.x], scnt[threadIdx.x]);
    __syncthreads();
    if (valid) {
        #pragma unroll
        for (int j = 0; j < 4; ++j) {
            int b = b_[j];
            bkt[(size_t)b * CAP + sbase[b] + r_[j]] = u_[j];
        }
    }
}

// ---------------- stage 2: per-XCD degree histogram from bucket ------------
__global__ __launch_bounds__(256) void k_hist2(const uint32_t* __restrict__ bkt,
                                               const int* __restrict__ bcnt,
                                               int* __restrict__ cnt) {
    const int xcd  = blockIdx.x & 7;
    const int blk  = blockIdx.x >> 3;
    const int nblk = (int)(gridDim.x >> 3);
    const int m = bcnt[xcd];
    const uint32_t* B = bkt + (size_t)xcd * CAP;
    const int lo = xcd * RNODES;
    for (int i = blk * 256 + threadIdx.x; i < m; i += nblk * 256)
        atomicAdd(&cnt[lo + (int)(B[i] >> 17)], 1);
}

// ---------------- exclusive scan (3 kernels) ----------------
__global__ __launch_bounds__(1024) void k_scan1(const int* __restrict__ cnt,
                                                int* __restrict__ excl,
                                                int* __restrict__ bsum, int n) {
    __shared__ int sh[1024];
    int i = blockIdx.x * 1024 + threadIdx.x;
    int v = (i < n) ? cnt[i] : 0;
    sh[threadIdx.x] = v;
    __syncthreads();
    for (int off = 1; off < 1024; off <<= 1) {
        int t = (threadIdx.x >= off) ? sh[threadIdx.x - off] : 0;
        __syncthreads();
        sh[threadIdx.x] += t;
        __syncthreads();
    }
    if (i < n) excl[i] = sh[threadIdx.x] - v;   // exclusive
    if (threadIdx.x == 1023) bsum[blockIdx.x] = sh[1023];
}

__global__ void k_scan2(int* __restrict__ bsum, int nb) {
    __shared__ int sh[128];
    int t = threadIdx.x;
    int v = (t < nb) ? bsum[t] : 0;
    sh[t] = v;
    __syncthreads();
    for (int off = 1; off < 128; off <<= 1) {
        int u = (t >= off) ? sh[t - off] : 0;
        __syncthreads();
        sh[t] += u;
        __syncthreads();
    }
    if (t < nb) bsum[t] = sh[t] - v;   // exclusive block offsets
}

// finalize row_ptr, init cursor, compute dis = rsqrt(deg+1)
__global__ void k_scan3(int* __restrict__ excl, const int* __restrict__ bsum,
                        int* __restrict__ cursor, const int* __restrict__ cnt,
                        float* __restrict__ dis, int n, int e) {
    int i = blockIdx.x * blockDim.x + threadIdx.x;
    if (i < n) {
        int v = excl[i] + bsum[i >> 10];
        excl[i] = v;
        cursor[i] = v;
        dis[i] = rsqrtf((float)(cnt[i] + 1));
    }
    if (i == 0) excl[n] = e;
}

// ---------------- stage 4: per-XCD CSR fill from bucket --------------------
__global__ __launch_bounds__(256) void k_fill2(const uint32_t* __restrict__ bkt,
                                               const int* __restrict__ bcnt,
                                               int* __restrict__ cursor,
                                               uint2* __restrict__ colw,
                                               const float* __restrict__ dis) {
    const int xcd  = blockIdx.x & 7;
    const int blk  = blockIdx.x >> 3;
    const int nblk = (int)(gridDim.x >> 3);
    const int m = bcnt[xcd];
    const uint32_t* B = bkt + (size_t)xcd * CAP;
    const int lo = xcd * RNODES;
    for (int i = blk * 256 + threadIdx.x; i < m; i += nblk * 256) {
        uint32_t u = B[i];
        int s = (int)(u & 0x1FFFFu);
        int d = lo + (int)(u >> 17);
        int pos = atomicAdd(&cursor[d], 1);
        uint2 cw;
        cw.x = (uint32_t)s;
        cw.y = __float_as_uint(dis[s] * dis[d]);
        colw[pos] = cw;
    }
}

// ---------------- MFMA GEMM: H[n x 128] = X[n x 128] @ Wb[128 x 128] -> bf16 -
// 256 thr = 4 waves; wave computes 16 rows x 128 cols via 16x16x32 bf16 MFMA.
// Wb is pre-converted bf16; LDS stage is a pure transpose copy.
// C/D mapping (m89-verified): col=lane&15, row=(lane>>4)*4+j.
template <typename TIN>
__global__ __launch_bounds__(256) void k_gemm(const TIN* __restrict__ X,
                                              const unsigned short* __restrict__ Wb,
                                              unsigned short* __restrict__ H, int n) {
    __shared__ unsigned short Wl[128][136];   // [n][k] bf16
    const int t = threadIdx.x;
    #pragma unroll
    for (int c = 0; c < 8; ++c) {
        int idx8 = (c * 256 + t) * 8;        // 8 bf16 = 16B, within-row (8 | 128)
        int k  = idx8 >> 7;
        int nn = idx8 & 127;
        ushort4 v0 = *(const ushort4*)(Wb + idx8);
        ushort4 v1 = *(const ushort4*)(Wb + idx8 + 4);
        Wl[nn + 0][k] = v0.x; Wl[nn + 1][k] = v0.y;
        Wl[nn + 2][k] = v0.z; Wl[nn + 3][k] = v0.w;
        Wl[nn + 4][k] = v1.x; Wl[nn + 5][k] = v1.y;
        Wl[nn + 6][k] = v1.z; Wl[nn + 7][k] = v1.w;
    }
    __syncthreads();

    const int wave = t >> 6, lane = t & 63;
    const int row0 = blockIdx.x * 64 + wave * 16;
    if (row0 >= n) return;
    const int arow = row0 + (lane & 15);
    const int kb8  = (lane >> 4) * 8;

    bf16x8 a[4];
    if constexpr (sizeof(TIN) == 4) {
        const float* Xf = (const float*)X;
        #pragma unroll
        for (int kt = 0; kt < 4; ++kt) {
            const float* p = Xf + (size_t)arow * FD + kt * 32 + kb8;
            float4 u0 = *(const float4*)p;
            float4 u1 = *(const float4*)(p + 4);
            bf16x8 f;
            f[0] = (short)bf1(u0.x); f[1] = (short)bf1(u0.y);
            f[2] = (short)bf1(u0.z); f[3] = (short)bf1(u0.w);
            f[4] = (short)bf1(u1.x); f[5] = (short)bf1(u1.y);
            f[6] = (short)bf1(u1.z); f[7] = (short)bf1(u1.w);
            a[kt] = f;
        }
    } else {
        const unsigned short* Xb = (const unsigned short*)X;
        #pragma unroll
        for (int kt = 0; kt < 4; ++kt)
            a[kt] = *(const bf16x8*)(Xb + (size_t)arow * FD + kt * 32 + kb8);
    }

    const int ccol  = lane & 15;
    const int crow0 = row0 + (lane >> 4) * 4;
    #pragma unroll
    for (int nt = 0; nt < 8; ++nt) {
        f32x4 acc = {0.f, 0.f, 0.f, 0.f};
        const int bcol = nt * 16 + (lane & 15);
        #pragma unroll
        for (int kt = 0; kt < 4; ++kt) {
            bf16x8 b = *(const bf16x8*)&Wl[bcol][kt * 32 + kb8];
            acc = __builtin_amdgcn_mfma_f32_16x16x32_bf16(a[kt], b, acc, 0, 0, 0);
        }
        #pragma unroll
        for (int j = 0; j < 4; ++j)
            H[(size_t)(crow0 + j) * FD + nt * 16 + ccol] = bf1(acc[j]);
    }
}

// ---------------- 128-wide aggregation over bf16 rows --------------------
// TWO nodes per wave (measured optimum: 32 in-flight loads, VGPR 44, occ 45%);
// per node ceil(deg/16) masked 16-deep gather groups. fp32 accumulation.
// MODE 0: writes relu rows (bf16). MODE 1: fused dot with W3 -> outf[i].
template <int MODE>
__global__ __launch_bounds__(256) void k_agg(const unsigned short* __restrict__ h,
                                             const float* __restrict__ dis,
                                             const int* __restrict__ rp,
                                             const uint2* __restrict__ colw,
                                             const float* __restrict__ bias,
                                             const float* __restrict__ W3,
                                             unsigned short* __restrict__ out,
                                             float* __restrict__ outf, int n) {
    const uint32_t* h32 = (const uint32_t*)h;   // 64 words per row
    int wid  = (int)((blockIdx.x * (size_t)blockDim.x + threadIdx.x) >> 6);
    int lane = threadIdx.x & 63;
    int w2 = __builtin_amdgcn_readfirstlane(wid);
    int i0 = 2 * w2;
    if (i0 >= n) return;
    int i1 = i0 + 1;
    const bool has1 = (i1 < n);

    const int e00 = rp[i0];
    const int e01 = rp[i0 + 1];
    const int e11 = has1 ? rp[i0 + 2] : e01;

    float di0 = dis[i0];
    float di1 = has1 ? dis[i1] : 0.f;
    float2 acc0, acc1;
    {
        uint32_t su0 = h32[(size_t)i0 * 64 + lane];
        float q0 = di0 * di0;
        acc0.x = bf_lo(su0) * q0; acc0.y = bf_hi(su0) * q0;
        if (has1) {
            uint32_t su1 = h32[(size_t)i1 * 64 + lane];
            float q1 = di1 * di1;
            acc1.x = bf_lo(su1) * q1; acc1.y = bf_hi(su1) * q1;
        } else { acc1.x = acc1.y = 0.f; }
    }

    const int ng0 = (e01 - e00 + 15) >> 4;
    const int ng1 = (e11 - e01 + 15) >> 4;
    const int ng  = ng0 > ng1 ? ng0 : ng1;

    for (int g = 0; g < ng; ++g) {
        const bool do0 = (g < ng0), do1 = (g < ng1);
        int s0[16], s1[16];
        float w0_[16], w1_[16];
        uint32_t v0[16], v1[16];
        if (do0) {
            const int jb = e00 + g * 16;
            if (jb + 16 <= e01) {
                #pragma unroll
                for (int q = 0; q < 16; ++q) {
                    uint2 cw = colw[jb + q];
                    s0[q] = (int)cw.x; w0_[q] = __uint_as_float(cw.y);
                }
            } else {
                #pragma unroll
                for (int q = 0; q < 16; ++q) {
                    int idx = jb + q;
                    int c   = idx < e01 ? idx : e01 - 1;
                    uint2 cw = colw[c];
                    s0[q]  = (int)cw.x;
                    w0_[q] = idx < e01 ? __uint_as_float(cw.y) : 0.f;
                }
            }
        }
        if (do1) {
            const int jb = e01 + g * 16;
            if (jb + 16 <= e11) {
                #pragma unroll
                for (int q = 0; q < 16; ++q) {
                    uint2 cw = colw[jb + q];
                    s1[q] = (int)cw.x; w1_[q] = __uint_as_float(cw.y);
                }
            } else {
                #pragma unroll
                for (int q = 0; q < 16; ++q) {
                    int idx = jb + q;
                    int c   = idx < e11 ? idx : e11 - 1;
                    uint2 cw = colw[c];
                    s1[q]  = (int)cw.x;
                    w1_[q] = idx < e11 ? __uint_as_float(cw.y) : 0.f;
                }
            }
        }
        if (do0) {
            #pragma unroll
            for (int q = 0; q < 16; ++q)
                v0[q] = h32[(size_t)s0[q] * 64 + lane];
        }
        if (do1) {
            #pragma unroll
            for (int q = 0; q < 16; ++q)
                v1[q] = h32[(size_t)s1[q] * 64 + lane];
        }
        if (do0) {
            #pragma unroll
            for (int q = 0; q < 16; ++q) {
                acc0.x = fmaf(w0_[q], bf_lo(v0[q]), acc0.x);
                acc0.y = fmaf(w0_[q], bf_hi(v0[q]), acc0.y);
            }
        }
        if (do1) {
            #pragma unroll
            for (int q = 0; q < 16; ++q) {
                acc1.x = fmaf(w1_[q], bf_lo(v1[q]), acc1.x);
                acc1.y = fmaf(w1_[q], bf_hi(v1[q]), acc1.y);
            }
        }
    }

    float2 b = ((const float2*)bias)[lane];
    acc0.x = fmaxf(acc0.x + b.x, 0.f);
    acc0.y = fmaxf(acc0.y + b.y, 0.f);
    acc1.x = fmaxf(acc1.x + b.x, 0.f);
    acc1.y = fmaxf(acc1.y + b.y, 0.f);

    if (MODE == 0) {
        ((uint32_t*)out)[(size_t)i0 * 64 + lane] = bf_pack(acc0.x, acc0.y);
        if (has1)
            ((uint32_t*)out)[(size_t)i1 * 64 + lane] = bf_pack(acc1.x, acc1.y);
    } else {
        float2 w3 = ((const float2*)W3)[lane];
        float d0 = acc0.x * w3.x + acc0.y * w3.y;
        float d1 = acc1.x * w3.x + acc1.y * w3.y;
        #pragma unroll
        for (int off = 32; off; off >>= 1) {
            d0 += __shfl_xor(d0, off);
            d1 += __shfl_xor(d1, off);
        }
        if (lane == 0) {
            outf[i0] = d0;
            if (has1) outf[i1] = d1;
        }
    }
}

// ---------------- scalar aggregation + bias + sigmoid (wave per node) ----------
__global__ __launch_bounds__(256) void k_agg1(const float* __restrict__ h3,
                                              const float* __restrict__ dis,
                                              const int* __restrict__ rp,
                                              const uint2* __restrict__ colw,
                                              const float* __restrict__ b3,
                                              float* __restrict__ out, int n) {
    int i    = (int)((blockIdx.x * (size_t)blockDim.x + threadIdx.x) >> 6);
    int lane = threadIdx.x & 63;
    if (i >= n) return;
    float di  = dis[i];
    float acc = (lane == 0) ? di * di * h3[i] : 0.f;
    const int e0 = rp[i], e1 = rp[i + 1];
    for (int base = e0 + lane; base < e1; base += 64) {
        uint2 cw = colw[base];
        acc = fmaf(__uint_as_float(cw.y), h3[(int)cw.x], acc);
    }
    #pragma unroll
    for (int off = 32; off; off >>= 1) acc += __shfl_xor(acc, off);
    if (lane == 0) {
        float v = acc + b3[0];
        out[i] = 1.f / (1.f + expf(-v));
    }
}

// ---------------- host launch ----------------
static inline size_t alg(size_t x) { return (x + 255) & ~(size_t)255; }

extern "C" void kernel_launch(void* const* d_in, const int* in_sizes, int n_in,
                              void* d_out, int out_size, void* d_ws, size_t ws_size,
                              hipStream_t stream) {
    const float* x   = (const float*)d_in[0];
    const int*   ei  = (const int*)d_in[1];     // [2, E]
    const float* W1  = (const float*)d_in[2];
    const float* b1  = (const float*)d_in[3];
    const float* W2  = (const float*)d_in[4];
    const float* b2  = (const float*)d_in[5];
    const float* W3  = (const float*)d_in[6];
    const float* b3  = (const float*)d_in[7];
    float*       out = (float*)d_out;

    const int n = NN, e = NE;
    const int* src = ei;
    const int* dst = ei + e;

    char* w = (char*)d_ws;
    float* dis    = (float*)w;  w += alg((size_t)n * 4);
    int*   cnt    = (int*)w;    w += alg((size_t)n * 4);
    int*   bcnt   = (int*)w;    w += alg((size_t)8 * 4);
    int*   rp     = (int*)w;    w += alg((size_t)(n + 1) * 4);
    int*   cursor = (int*)w;    w += alg((size_t)n * 4);
    int*   bsum   = (int*)w;    w += alg((size_t)128 * 4);
    uint32_t* bkt = (uint32_t*)w; w += alg((size_t)NXCD * CAP * 4);
    uint2* colw   = (uint2*)w;  w += alg((size_t)e * 8);
    unsigned short* bufA = (unsigned short*)w; w += alg((size_t)n * FD * 2);
    unsigned short* bufB = (unsigned short*)w; w += alg((size_t)n * FD * 2);
    unsigned short* Wb1  = (unsigned short*)w; w += alg((size_t)FD * FD * 2);
    unsigned short* Wb2  = (unsigned short*)w; w += alg((size_t)FD * FD * 2);
    float* h3     = (float*)w;  w += alg((size_t)n * 4);

    hipMemsetAsync(cnt, 0, (size_t)n * 4, stream);
    hipMemsetAsync(bcnt, 0, 8 * 4, stream);

    const int B = 256;
    const int gN = (n + B - 1) / B;
    const int nScan = (n + 1023) / 1024;   // 98
    const int nChunk = (e + 1023) / 1024;  // 1563

    k_wcvt<<<16, B, 0, stream>>>(W1, W2, Wb1, Wb2);
    k_part<<<nChunk, B, 0, stream>>>(src, dst, bkt, bcnt, e);
    k_hist2<<<2048, B, 0, stream>>>(bkt, bcnt, cnt);
    k_scan1<<<nScan, 1024, 0, stream>>>(cnt, rp, bsum, n);
    k_scan2<<<1, 128, 0, stream>>>(bsum, nScan);
    k_scan3<<<gN, B, 0, stream>>>(rp, bsum, cursor, cnt, dis, n, e);
    k_fill2<<<2048, B, 0, stream>>>(bkt, bcnt, cursor, colw, dis);

    const int gGemm = (n + 63) / 64;                    // 1563
    const int nWave2 = (n + 1) / 2;                     // two nodes per wave
    const int gWave2 = (nWave2 * 64 + B - 1) / B;       // blocks for k_agg
    const int gWave  = (n * 64 + B - 1) / B;            // wave per node (k_agg1)

    // layer 1
    k_gemm<float><<<gGemm, B, 0, stream>>>(x, Wb1, bufA, n);
    k_agg<0><<<gWave2, B, 0, stream>>>(bufA, dis, rp, colw, b1, W3, bufB, h3, n);
    // layer 2 (+ fused layer-3 matvec)
    k_gemm<unsigned short><<<gGemm, B, 0, stream>>>(bufB, Wb2, bufA, n);
    k_agg<1><<<gWave2, B, 0, stream>>>(bufA, dis, rp, colw, b2, W3, bufB, h3, n);
    // layer 3
    k_agg1<<<gWave, B, 0, stream>>>(h3, dis, rp, colw, b3, out, n);
}